// Round 1
// baseline (3346.333 us; speedup 1.0000x reference)
//
#include <hip/hip_runtime.h>

#define N_NODES  100000
#define N_EDGES  1600000
#define N_GRAPHS 512
#define IN_DIM   128
#define HID_DIM  256
#define OUT_DIM  128

// ---------------- init: A = x (copy, since eps=0 -> h = x + agg) ----------------
__global__ __launch_bounds__(256) void copy_f4(const float4* __restrict__ src,
                                               float4* __restrict__ dst, int n4) {
    int i = blockIdx.x * blockDim.x + threadIdx.x;
    if (i < n4) dst[i] = src[i];
}

// ---------------- scatter add: A[dst] += x[src] ----------------
// 32 threads per edge, each handles 4 consecutive feats (float4 gather, 4 atomics)
__global__ __launch_bounds__(256) void scatter_add_kernel(const float* __restrict__ x,
                                                          const int* __restrict__ ei,
                                                          float* __restrict__ A,
                                                          int nEdges) {
    long long idx = (long long)blockIdx.x * blockDim.x + threadIdx.x;
    int e = (int)(idx >> 5);
    if (e >= nEdges) return;
    int lane = (int)(idx & 31);
    int s = ei[e];
    int d = ei[nEdges + e];
    float4 v = *(const float4*)(x + (size_t)s * IN_DIM + lane * 4);
    float* out = A + (size_t)d * IN_DIM + lane * 4;
    atomicAdd(out + 0, v.x);
    atomicAdd(out + 1, v.y);
    atomicAdd(out + 2, v.z);
    atomicAdd(out + 3, v.w);
}

// ---------------- fp32 tiled GEMM: C = act(A @ B + bias), optional pooled scatter ----------------
// A: MxK row-major, B: KxN row-major. BM=64 BN=64 BK=32, 256 thr, 4x4 microtile.
template <bool RELU, bool POOL>
__global__ __launch_bounds__(256) void gemm_kernel(const float* __restrict__ A,
                                                   const float* __restrict__ B,
                                                   const float* __restrict__ bias,
                                                   float* __restrict__ C,
                                                   const int* __restrict__ batch,
                                                   int M, int N, int K) {
    const int BM = 64, BN = 64, BK = 32;
    __shared__ float As[BM][BK + 4];  // +4 pad keeps float4 alignment, breaks pow2 stride
    __shared__ float Bs[BK][BN];

    int tid = threadIdx.x;
    int block_row = blockIdx.x * BM;
    int block_col = blockIdx.y * BN;
    int tr = (tid / 16) * 4;  // 0..60
    int tc = (tid % 16) * 4;  // 0..60

    float acc[4][4] = {};

    for (int kt = 0; kt < K; kt += BK) {
        // load A tile: 64 rows x 32 k = 512 float4, 2 per thread
        #pragma unroll
        for (int i = 0; i < 2; ++i) {
            int l = tid * 2 + i;        // 0..511
            int m = l >> 3;             // 0..63
            int k0 = (l & 7) * 4;       // 0..28
            int row = block_row + m;
            float4 v = make_float4(0.f, 0.f, 0.f, 0.f);
            if (row < M) v = *(const float4*)(A + (size_t)row * K + kt + k0);
            *(float4*)&As[m][k0] = v;
        }
        // load B tile: 32 k x 64 n = 512 float4, 2 per thread
        #pragma unroll
        for (int i = 0; i < 2; ++i) {
            int l = tid * 2 + i;        // 0..511
            int k = l >> 4;             // 0..31
            int n0 = (l & 15) * 4;      // 0..60
            float4 v = *(const float4*)(B + (size_t)(kt + k) * N + block_col + n0);
            *(float4*)&Bs[k][n0] = v;
        }
        __syncthreads();

        #pragma unroll
        for (int k = 0; k < BK; ++k) {
            float4 b4 = *(const float4*)&Bs[k][tc];
            float a0 = As[tr + 0][k];
            float a1 = As[tr + 1][k];
            float a2 = As[tr + 2][k];
            float a3 = As[tr + 3][k];
            acc[0][0] += a0 * b4.x; acc[0][1] += a0 * b4.y; acc[0][2] += a0 * b4.z; acc[0][3] += a0 * b4.w;
            acc[1][0] += a1 * b4.x; acc[1][1] += a1 * b4.y; acc[1][2] += a1 * b4.z; acc[1][3] += a1 * b4.w;
            acc[2][0] += a2 * b4.x; acc[2][1] += a2 * b4.y; acc[2][2] += a2 * b4.z; acc[2][3] += a2 * b4.w;
            acc[3][0] += a3 * b4.x; acc[3][1] += a3 * b4.y; acc[3][2] += a3 * b4.z; acc[3][3] += a3 * b4.w;
        }
        __syncthreads();
    }

    // epilogue
    #pragma unroll
    for (int i = 0; i < 4; ++i) {
        int row = block_row + tr + i;
        if (row >= M) continue;
        if (POOL) {
            int g = batch[row];
            #pragma unroll
            for (int j = 0; j < 4; ++j) {
                int col = block_col + tc + j;
                float v = acc[i][j] + bias[col];
                if (RELU) v = fmaxf(v, 0.f);
                atomicAdd(&C[(size_t)g * N + col], v);
            }
        } else {
            #pragma unroll
            for (int j = 0; j < 4; ++j) {
                int col = block_col + tc + j;
                float v = acc[i][j] + bias[col];
                if (RELU) v = fmaxf(v, 0.f);
                C[(size_t)row * N + col] = v;
            }
        }
    }
}

extern "C" void kernel_launch(void* const* d_in, const int* in_sizes, int n_in,
                              void* d_out, int out_size, void* d_ws, size_t ws_size,
                              hipStream_t stream) {
    const float* x  = (const float*)d_in[0];
    const int*   ei = (const int*)d_in[1];     // [2, E] int32
    const int*   bi = (const int*)d_in[2];     // [N] int32, sorted
    const float* W1 = (const float*)d_in[3];
    const float* b1 = (const float*)d_in[4];
    const float* W2 = (const float*)d_in[5];
    const float* b2 = (const float*)d_in[6];
    const float* Wo = (const float*)d_in[7];
    const float* bo = (const float*)d_in[8];
    float* out = (float*)d_out;

    float* A  = (float*)d_ws;                          // [N, 128]
    float* H1 = A  + (size_t)N_NODES * IN_DIM;         // [N, 256]
    float* H2 = H1 + (size_t)N_NODES * HID_DIM;        // [N, 256]

    // zero output accumulator (harness poisons it before every launch)
    hipMemsetAsync(d_out, 0, (size_t)N_GRAPHS * OUT_DIM * sizeof(float), stream);

    // A = x
    {
        int n4 = N_NODES * IN_DIM / 4;
        copy_f4<<<(n4 + 255) / 256, 256, 0, stream>>>((const float4*)x, (float4*)A, n4);
    }
    // A[dst] += x[src]
    {
        long long threads = (long long)N_EDGES * 32;
        int blocks = (int)((threads + 255) / 256);
        scatter_add_kernel<<<blocks, 256, 0, stream>>>(x, ei, A, N_EDGES);
    }
    // H1 = relu(A @ W1 + b1)
    {
        dim3 grid((N_NODES + 63) / 64, HID_DIM / 64);
        gemm_kernel<true, false><<<grid, 256, 0, stream>>>(A, W1, b1, H1, nullptr,
                                                           N_NODES, HID_DIM, IN_DIM);
    }
    // H2 = relu(H1 @ W2 + b2)
    {
        dim3 grid((N_NODES + 63) / 64, HID_DIM / 64);
        gemm_kernel<true, false><<<grid, 256, 0, stream>>>(H1, W2, b2, H2, nullptr,
                                                           N_NODES, HID_DIM, HID_DIM);
    }
    // out = H2 @ Wo + bo, pooled into d_out by batch id
    {
        dim3 grid((N_NODES + 63) / 64, OUT_DIM / 64);
        gemm_kernel<false, true><<<grid, 256, 0, stream>>>(H2, Wo, bo, out, bi,
                                                           N_NODES, OUT_DIM, HID_DIM);
    }
}

// Round 2
// 945.058 us; speedup vs baseline: 3.5409x; 3.5409x over previous
//
#include <hip/hip_runtime.h>

#define N_NODES  100000
#define N_EDGES  1600000
#define N_GRAPHS 512
#define IN_DIM   128
#define HID_DIM  256
#define OUT_DIM  128

#define SCAN_B   256
#define NUM_SCAN_BLOCKS ((N_NODES + SCAN_B - 1) / SCAN_B)   // 391

// ---------------- degree histogram ----------------
__global__ __launch_bounds__(256) void hist_kernel(const int* __restrict__ ei,
                                                   int* __restrict__ deg) {
    int e = blockIdx.x * blockDim.x + threadIdx.x;
    if (e < N_EDGES) atomicAdd(&deg[ei[N_EDGES + e]], 1);
}

// ---------------- scan step 1: per-block sums ----------------
__global__ __launch_bounds__(SCAN_B) void block_sum_kernel(const int* __restrict__ deg,
                                                           int* __restrict__ blockSums) {
    __shared__ int s[SCAN_B];
    int i = blockIdx.x * SCAN_B + threadIdx.x;
    s[threadIdx.x] = (i < N_NODES) ? deg[i] : 0;
    __syncthreads();
    for (int st = SCAN_B / 2; st > 0; st >>= 1) {
        if (threadIdx.x < st) s[threadIdx.x] += s[threadIdx.x + st];
        __syncthreads();
    }
    if (threadIdx.x == 0) blockSums[blockIdx.x] = s[0];
}

// ---------------- scan step 2: exclusive scan of block sums (single block) ----------------
__global__ __launch_bounds__(512) void scan_blocksums_kernel(const int* __restrict__ blockSums,
                                                             int* __restrict__ blockPrefix) {
    __shared__ int s[512];
    int t = threadIdx.x;
    int v = (t < NUM_SCAN_BLOCKS) ? blockSums[t] : 0;
    s[t] = v;
    __syncthreads();
    for (int st = 1; st < 512; st <<= 1) {
        int add = (t >= st) ? s[t - st] : 0;
        __syncthreads();
        s[t] += add;
        __syncthreads();
    }
    if (t < NUM_SCAN_BLOCKS) blockPrefix[t] = s[t] - v;  // exclusive
}

// ---------------- scan step 3: final offsets + cursor init ----------------
__global__ __launch_bounds__(SCAN_B) void scan_final_kernel(const int* __restrict__ deg,
                                                            const int* __restrict__ blockPrefix,
                                                            int* __restrict__ offsets,
                                                            int* __restrict__ cursor) {
    __shared__ int s[SCAN_B];
    int i = blockIdx.x * SCAN_B + threadIdx.x;
    int v = (i < N_NODES) ? deg[i] : 0;
    s[threadIdx.x] = v;
    __syncthreads();
    for (int st = 1; st < SCAN_B; st <<= 1) {
        int add = (threadIdx.x >= st) ? s[threadIdx.x - st] : 0;
        __syncthreads();
        s[threadIdx.x] += add;
        __syncthreads();
    }
    if (i < N_NODES) {
        int excl = blockPrefix[blockIdx.x] + s[threadIdx.x] - v;
        offsets[i] = excl;
        cursor[i] = excl;
    }
}

// ---------------- scatter src ids into CSR buckets ----------------
__global__ __launch_bounds__(256) void scatter_edges_kernel(const int* __restrict__ ei,
                                                            int* __restrict__ cursor,
                                                            int* __restrict__ nbr) {
    int e = blockIdx.x * blockDim.x + threadIdx.x;
    if (e < N_EDGES) {
        int d = ei[N_EDGES + e];
        int s = ei[e];
        int pos = atomicAdd(&cursor[d], 1);
        nbr[pos] = s;
    }
}

// ---------------- gather aggregate: A[v] = x[v] + sum_{s in nbr(v)} x[s] ----------------
// one 64-lane wave per node; float2 per lane (128 feats)
__global__ __launch_bounds__(256) void aggregate_kernel(const float2* __restrict__ x2,
                                                        const int* __restrict__ offsets,
                                                        const int* __restrict__ deg,
                                                        const int* __restrict__ nbr,
                                                        float2* __restrict__ A2) {
    int v = blockIdx.x * 4 + (threadIdx.x >> 6);
    v = __builtin_amdgcn_readfirstlane(v);   // wave-uniform -> scalar loads below
    int lane = threadIdx.x & 63;
    if (v >= N_NODES) return;
    int off = offsets[v];
    int len = deg[v];
    const float2* xrow = x2 + (size_t)v * (IN_DIM / 2);
    float2 acc = xrow[lane];
    int i = 0;
    for (; i + 4 <= len; i += 4) {
        int s0 = nbr[off + i + 0];
        int s1 = nbr[off + i + 1];
        int s2 = nbr[off + i + 2];
        int s3 = nbr[off + i + 3];
        float2 a0 = x2[(size_t)s0 * (IN_DIM / 2) + lane];
        float2 a1 = x2[(size_t)s1 * (IN_DIM / 2) + lane];
        float2 a2 = x2[(size_t)s2 * (IN_DIM / 2) + lane];
        float2 a3 = x2[(size_t)s3 * (IN_DIM / 2) + lane];
        acc.x += a0.x + a1.x + a2.x + a3.x;
        acc.y += a0.y + a1.y + a2.y + a3.y;
    }
    for (; i < len; ++i) {
        int s = nbr[off + i];
        float2 a = x2[(size_t)s * (IN_DIM / 2) + lane];
        acc.x += a.x;
        acc.y += a.y;
    }
    A2[(size_t)v * (IN_DIM / 2) + lane] = acc;
}

// ---------------- fp32 tiled GEMM: C = act(A @ B + bias), optional pooled scatter ----------------
template <bool RELU, bool POOL>
__global__ __launch_bounds__(256) void gemm_kernel(const float* __restrict__ A,
                                                   const float* __restrict__ B,
                                                   const float* __restrict__ bias,
                                                   float* __restrict__ C,
                                                   const int* __restrict__ batch,
                                                   int M, int N, int K) {
    const int BM = 64, BN = 64, BK = 32;
    __shared__ float As[BM][BK + 4];
    __shared__ float Bs[BK][BN];

    int tid = threadIdx.x;
    int block_row = blockIdx.x * BM;
    int block_col = blockIdx.y * BN;
    int tr = (tid / 16) * 4;
    int tc = (tid % 16) * 4;

    float acc[4][4] = {};

    for (int kt = 0; kt < K; kt += BK) {
        #pragma unroll
        for (int i = 0; i < 2; ++i) {
            int l = tid * 2 + i;
            int m = l >> 3;
            int k0 = (l & 7) * 4;
            int row = block_row + m;
            float4 v = make_float4(0.f, 0.f, 0.f, 0.f);
            if (row < M) v = *(const float4*)(A + (size_t)row * K + kt + k0);
            *(float4*)&As[m][k0] = v;
        }
        #pragma unroll
        for (int i = 0; i < 2; ++i) {
            int l = tid * 2 + i;
            int k = l >> 4;
            int n0 = (l & 15) * 4;
            float4 v = *(const float4*)(B + (size_t)(kt + k) * N + block_col + n0);
            *(float4*)&Bs[k][n0] = v;
        }
        __syncthreads();

        #pragma unroll
        for (int k = 0; k < BK; ++k) {
            float4 b4 = *(const float4*)&Bs[k][tc];
            float a0 = As[tr + 0][k];
            float a1 = As[tr + 1][k];
            float a2 = As[tr + 2][k];
            float a3 = As[tr + 3][k];
            acc[0][0] += a0 * b4.x; acc[0][1] += a0 * b4.y; acc[0][2] += a0 * b4.z; acc[0][3] += a0 * b4.w;
            acc[1][0] += a1 * b4.x; acc[1][1] += a1 * b4.y; acc[1][2] += a1 * b4.z; acc[1][3] += a1 * b4.w;
            acc[2][0] += a2 * b4.x; acc[2][1] += a2 * b4.y; acc[2][2] += a2 * b4.z; acc[2][3] += a2 * b4.w;
            acc[3][0] += a3 * b4.x; acc[3][1] += a3 * b4.y; acc[3][2] += a3 * b4.z; acc[3][3] += a3 * b4.w;
        }
        __syncthreads();
    }

    #pragma unroll
    for (int i = 0; i < 4; ++i) {
        int row = block_row + tr + i;
        if (row >= M) continue;
        if (POOL) {
            int g = batch[row];
            #pragma unroll
            for (int j = 0; j < 4; ++j) {
                int col = block_col + tc + j;
                float v = acc[i][j] + bias[col];
                if (RELU) v = fmaxf(v, 0.f);
                atomicAdd(&C[(size_t)g * N + col], v);
            }
        } else {
            #pragma unroll
            for (int j = 0; j < 4; ++j) {
                int col = block_col + tc + j;
                float v = acc[i][j] + bias[col];
                if (RELU) v = fmaxf(v, 0.f);
                C[(size_t)row * N + col] = v;
            }
        }
    }
}

extern "C" void kernel_launch(void* const* d_in, const int* in_sizes, int n_in,
                              void* d_out, int out_size, void* d_ws, size_t ws_size,
                              hipStream_t stream) {
    const float* x  = (const float*)d_in[0];
    const int*   ei = (const int*)d_in[1];
    const int*   bi = (const int*)d_in[2];
    const float* W1 = (const float*)d_in[3];
    const float* b1 = (const float*)d_in[4];
    const float* W2 = (const float*)d_in[5];
    const float* b2 = (const float*)d_in[6];
    const float* Wo = (const float*)d_in[7];
    const float* bo = (const float*)d_in[8];
    float* out = (float*)d_out;

    float* A  = (float*)d_ws;                          // [N, 128]   51.2 MB
    float* H1 = A  + (size_t)N_NODES * IN_DIM;         // [N, 256]  102.4 MB
    float* H2 = H1 + (size_t)N_NODES * HID_DIM;        // [N, 256]  102.4 MB

    // CSR scratch aliased into H2's region (fully consumed before GEMM2 writes H2)
    int* deg         = (int*)H2;                       // [N]
    int* offsets     = deg + N_NODES;                  // [N]
    int* cursor      = offsets + N_NODES;              // [N]
    int* nbr         = cursor + N_NODES;               // [E]
    int* blockSums   = nbr + N_EDGES;                  // [391]
    int* blockPrefix = blockSums + NUM_SCAN_BLOCKS;    // [391]

    hipMemsetAsync(d_out, 0, (size_t)N_GRAPHS * OUT_DIM * sizeof(float), stream);
    hipMemsetAsync(deg, 0, (size_t)N_NODES * sizeof(int), stream);

    // ---- build CSR ----
    hist_kernel<<<(N_EDGES + 255) / 256, 256, 0, stream>>>(ei, deg);
    block_sum_kernel<<<NUM_SCAN_BLOCKS, SCAN_B, 0, stream>>>(deg, blockSums);
    scan_blocksums_kernel<<<1, 512, 0, stream>>>(blockSums, blockPrefix);
    scan_final_kernel<<<NUM_SCAN_BLOCKS, SCAN_B, 0, stream>>>(deg, blockPrefix, offsets, cursor);
    scatter_edges_kernel<<<(N_EDGES + 255) / 256, 256, 0, stream>>>(ei, cursor, nbr);

    // ---- aggregate: A = x + gather-sum ----
    aggregate_kernel<<<(N_NODES + 3) / 4, 256, 0, stream>>>((const float2*)x, offsets, deg,
                                                            nbr, (float2*)A);

    // ---- MLP ----
    {
        dim3 grid((N_NODES + 63) / 64, HID_DIM / 64);
        gemm_kernel<true, false><<<grid, 256, 0, stream>>>(A, W1, b1, H1, nullptr,
                                                           N_NODES, HID_DIM, IN_DIM);
    }
    {
        dim3 grid((N_NODES + 63) / 64, HID_DIM / 64);
        gemm_kernel<true, false><<<grid, 256, 0, stream>>>(H1, W2, b2, H2, nullptr,
                                                           N_NODES, HID_DIM, HID_DIM);
    }
    {
        dim3 grid((N_NODES + 63) / 64, OUT_DIM / 64);
        gemm_kernel<false, true><<<grid, 256, 0, stream>>>(H2, Wo, bo, out, bi,
                                                           N_NODES, OUT_DIM, HID_DIM);
    }
}

// Round 3
// 596.381 us; speedup vs baseline: 5.6111x; 1.5847x over previous
//
#include <hip/hip_runtime.h>

#define N_NODES  100000
#define M_PAD    100096   // padded to multiple of 128 for GEMM tiles
#define N_EDGES  1600000
#define N_GRAPHS 512
#define IN_DIM   128
#define HID_DIM  256
#define OUT_DIM  128

#define SCAN_B   256
#define NUM_SCAN_BLOCKS ((N_NODES + SCAN_B - 1) / SCAN_B)   // 391

typedef __bf16 bf16x8 __attribute__((ext_vector_type(8)));
typedef __bf16 bf16x2 __attribute__((ext_vector_type(2)));
typedef float  f32x4  __attribute__((ext_vector_type(4)));

__device__ __forceinline__ void async16(const void* g, void* l) {
    __builtin_amdgcn_global_load_lds(
        (const __attribute__((address_space(1))) unsigned int*)g,
        (__attribute__((address_space(3))) unsigned int*)l, 16, 0, 0);
}

// ---------------- degree histogram ----------------
__global__ __launch_bounds__(256) void hist_kernel(const int* __restrict__ ei,
                                                   int* __restrict__ deg) {
    int e = blockIdx.x * blockDim.x + threadIdx.x;
    if (e < N_EDGES) atomicAdd(&deg[ei[N_EDGES + e]], 1);
}

// ---------------- scan step 1: per-block sums ----------------
__global__ __launch_bounds__(SCAN_B) void block_sum_kernel(const int* __restrict__ deg,
                                                           int* __restrict__ blockSums) {
    __shared__ int s[SCAN_B];
    int i = blockIdx.x * SCAN_B + threadIdx.x;
    s[threadIdx.x] = (i < N_NODES) ? deg[i] : 0;
    __syncthreads();
    for (int st = SCAN_B / 2; st > 0; st >>= 1) {
        if (threadIdx.x < st) s[threadIdx.x] += s[threadIdx.x + st];
        __syncthreads();
    }
    if (threadIdx.x == 0) blockSums[blockIdx.x] = s[0];
}

// ---------------- scan step 2: exclusive scan of block sums ----------------
__global__ __launch_bounds__(512) void scan_blocksums_kernel(const int* __restrict__ blockSums,
                                                             int* __restrict__ blockPrefix) {
    __shared__ int s[512];
    int t = threadIdx.x;
    int v = (t < NUM_SCAN_BLOCKS) ? blockSums[t] : 0;
    s[t] = v;
    __syncthreads();
    for (int st = 1; st < 512; st <<= 1) {
        int add = (t >= st) ? s[t - st] : 0;
        __syncthreads();
        s[t] += add;
        __syncthreads();
    }
    if (t < NUM_SCAN_BLOCKS) blockPrefix[t] = s[t] - v;
}

// ---------------- scan step 3: final offsets + cursor init ----------------
__global__ __launch_bounds__(SCAN_B) void scan_final_kernel(const int* __restrict__ deg,
                                                            const int* __restrict__ blockPrefix,
                                                            int* __restrict__ offsets,
                                                            int* __restrict__ cursor) {
    __shared__ int s[SCAN_B];
    int i = blockIdx.x * SCAN_B + threadIdx.x;
    int v = (i < N_NODES) ? deg[i] : 0;
    s[threadIdx.x] = v;
    __syncthreads();
    for (int st = 1; st < SCAN_B; st <<= 1) {
        int add = (threadIdx.x >= st) ? s[threadIdx.x - st] : 0;
        __syncthreads();
        s[threadIdx.x] += add;
        __syncthreads();
    }
    if (i < N_NODES) {
        int excl = blockPrefix[blockIdx.x] + s[threadIdx.x] - v;
        offsets[i] = excl;
        cursor[i] = excl;
    }
}

// ---------------- scatter src ids into CSR buckets ----------------
__global__ __launch_bounds__(256) void scatter_edges_kernel(const int* __restrict__ ei,
                                                            int* __restrict__ cursor,
                                                            int* __restrict__ nbr) {
    int e = blockIdx.x * blockDim.x + threadIdx.x;
    if (e < N_EDGES) {
        int d = ei[N_EDGES + e];
        int s = ei[e];
        int pos = atomicAdd(&cursor[d], 1);
        nbr[pos] = s;
    }
}

// ---------------- gather aggregate: A[v] = bf16(x[v] + sum_{s in nbr(v)} x[s]) ----------------
__global__ __launch_bounds__(256) void aggregate_kernel(const float2* __restrict__ x2,
                                                        const int* __restrict__ offsets,
                                                        const int* __restrict__ deg,
                                                        const int* __restrict__ nbr,
                                                        __bf16* __restrict__ A) {
    int v = blockIdx.x * 4 + (threadIdx.x >> 6);
    v = __builtin_amdgcn_readfirstlane(v);
    int lane = threadIdx.x & 63;
    if (v >= N_NODES) return;
    int off = offsets[v];
    int len = deg[v];
    float2 acc = x2[(size_t)v * (IN_DIM / 2) + lane];
    int i = 0;
    for (; i + 4 <= len; i += 4) {
        int s0 = nbr[off + i + 0];
        int s1 = nbr[off + i + 1];
        int s2 = nbr[off + i + 2];
        int s3 = nbr[off + i + 3];
        float2 a0 = x2[(size_t)s0 * (IN_DIM / 2) + lane];
        float2 a1 = x2[(size_t)s1 * (IN_DIM / 2) + lane];
        float2 a2 = x2[(size_t)s2 * (IN_DIM / 2) + lane];
        float2 a3 = x2[(size_t)s3 * (IN_DIM / 2) + lane];
        acc.x += a0.x + a1.x + a2.x + a3.x;
        acc.y += a0.y + a1.y + a2.y + a3.y;
    }
    for (; i < len; ++i) {
        int s = nbr[off + i];
        float2 a = x2[(size_t)s * (IN_DIM / 2) + lane];
        acc.x += a.x;
        acc.y += a.y;
    }
    bf16x2 h;
    h.x = (__bf16)acc.x;
    h.y = (__bf16)acc.y;
    *(bf16x2*)(A + (size_t)v * IN_DIM + lane * 2) = h;
}

// ---------------- weight convert + transpose: Wt[n][k] = bf16(W[k][n]) ----------------
__global__ __launch_bounds__(256) void convert_transpose_kernel(const float* __restrict__ W,
                                                                __bf16* __restrict__ Wt,
                                                                int K, int N) {
    int i = blockIdx.x * blockDim.x + threadIdx.x;
    if (i < K * N) {
        int k = i / N, n = i % N;
        Wt[(size_t)n * K + k] = (__bf16)W[i];
    }
}

// ---------------- bf16 MFMA GEMM: C = act(A @ Bt^T + bias) ----------------
// A: [Mpad][K] bf16 row-major; Bt: [N][K] bf16 (i.e. B transposed).
// 128x128 tile, BK=32, 256 threads = 4 waves in 2x2, each wave 4x4 of 16x16x32 MFMA.
template <int K, bool RELU, bool POOL>
__global__ __launch_bounds__(256) void gemm_bf16(const __bf16* __restrict__ A,
                                                 const __bf16* __restrict__ Bt,
                                                 const float* __restrict__ bias,
                                                 void* __restrict__ C,
                                                 const int* __restrict__ batch,
                                                 int M, int N) {
    __shared__ __bf16 As[128 * 32];
    __shared__ __bf16 Bs[128 * 32];

    int tid = threadIdx.x;
    int wave = tid >> 6, lane = tid & 63;
    int quad = lane >> 4, l16 = lane & 15;
    size_t block_row = (size_t)blockIdx.x * 128;
    int block_col = blockIdx.y * 128;
    int wrow = (wave >> 1) * 64, wcol = (wave & 1) * 64;

    const __bf16* Abase = A + block_row * K;
    const __bf16* Bbase = Bt + (size_t)block_col * K;

    f32x4 acc[4][4] = {};

    #pragma unroll
    for (int kt = 0; kt < K; kt += 32) {
        // stage A & B tiles: each 128 rows x 32 k x 2B = 8192 B = 512 x 16B chunks
        #pragma unroll
        for (int i = 0; i < 2; ++i) {
            int c = i * 256 + tid;       // 0..511
            int row = c >> 2;            // 0..127
            int sub = c & 3;             // 16B chunk within 64B row
            async16(Abase + (size_t)row * K + kt + sub * 8, (char*)As + c * 16);
            async16(Bbase + (size_t)row * K + kt + sub * 8, (char*)Bs + c * 16);
        }
        __syncthreads();   // drains vmcnt(0) before barrier

        bf16x8 a[4], b[4];
        #pragma unroll
        for (int i = 0; i < 4; ++i) {
            a[i] = *(const bf16x8*)(As + (wrow + i * 16 + l16) * 32 + quad * 8);
            b[i] = *(const bf16x8*)(Bs + (wcol + i * 16 + l16) * 32 + quad * 8);
        }
        #pragma unroll
        for (int i = 0; i < 4; ++i)
            #pragma unroll
            for (int j = 0; j < 4; ++j)
                acc[i][j] = __builtin_amdgcn_mfma_f32_16x16x32_bf16(a[i], b[j], acc[i][j], 0, 0, 0);
        __syncthreads();
    }

    // epilogue: C/D layout col=lane&15, row=quad*4+reg
    #pragma unroll
    for (int i = 0; i < 4; ++i) {
        #pragma unroll
        for (int r = 0; r < 4; ++r) {
            size_t m = block_row + wrow + i * 16 + quad * 4 + r;
            if (m >= (size_t)M) continue;
            #pragma unroll
            for (int j = 0; j < 4; ++j) {
                int n = block_col + wcol + j * 16 + l16;
                float v = acc[i][j][r] + bias[n];
                if (RELU) v = fmaxf(v, 0.f);
                if (POOL) {
                    int g = batch[m];
                    atomicAdd((float*)C + (size_t)g * N + n, v);
                } else {
                    ((__bf16*)C)[m * N + n] = (__bf16)v;
                }
            }
        }
    }
}

extern "C" void kernel_launch(void* const* d_in, const int* in_sizes, int n_in,
                              void* d_out, int out_size, void* d_ws, size_t ws_size,
                              hipStream_t stream) {
    const float* x  = (const float*)d_in[0];
    const int*   ei = (const int*)d_in[1];
    const int*   bi = (const int*)d_in[2];
    const float* W1 = (const float*)d_in[3];
    const float* b1 = (const float*)d_in[4];
    const float* W2 = (const float*)d_in[5];
    const float* b2 = (const float*)d_in[6];
    const float* Wo = (const float*)d_in[7];
    const float* bo = (const float*)d_in[8];
    float* out = (float*)d_out;

    // ---- workspace layout (bf16 region first, then int CSR region) ----
    __bf16* A   = (__bf16*)d_ws;                       // [M_PAD][128]
    __bf16* H1  = A   + (size_t)M_PAD * IN_DIM;        // [M_PAD][256]
    __bf16* H2  = H1  + (size_t)M_PAD * HID_DIM;       // [M_PAD][256]
    __bf16* W1t = H2  + (size_t)M_PAD * HID_DIM;       // [256][128]
    __bf16* W2t = W1t + IN_DIM * HID_DIM;              // [256][256]
    __bf16* Wot = W2t + HID_DIM * HID_DIM;             // [128][256]
    int* deg         = (int*)(Wot + HID_DIM * OUT_DIM);
    int* offsets     = deg + N_NODES;
    int* cursor      = offsets + N_NODES;
    int* nbr         = cursor + N_NODES;
    int* blockSums   = nbr + N_EDGES;
    int* blockPrefix = blockSums + NUM_SCAN_BLOCKS;

    hipMemsetAsync(d_out, 0, (size_t)N_GRAPHS * OUT_DIM * sizeof(float), stream);
    hipMemsetAsync(deg, 0, (size_t)N_NODES * sizeof(int), stream);

    // ---- weight conversion (tiny) ----
    convert_transpose_kernel<<<(IN_DIM * HID_DIM + 255) / 256, 256, 0, stream>>>(W1, W1t, IN_DIM, HID_DIM);
    convert_transpose_kernel<<<(HID_DIM * HID_DIM + 255) / 256, 256, 0, stream>>>(W2, W2t, HID_DIM, HID_DIM);
    convert_transpose_kernel<<<(HID_DIM * OUT_DIM + 255) / 256, 256, 0, stream>>>(Wo, Wot, HID_DIM, OUT_DIM);

    // ---- build CSR ----
    hist_kernel<<<(N_EDGES + 255) / 256, 256, 0, stream>>>(ei, deg);
    block_sum_kernel<<<NUM_SCAN_BLOCKS, SCAN_B, 0, stream>>>(deg, blockSums);
    scan_blocksums_kernel<<<1, 512, 0, stream>>>(blockSums, blockPrefix);
    scan_final_kernel<<<NUM_SCAN_BLOCKS, SCAN_B, 0, stream>>>(deg, blockPrefix, offsets, cursor);
    scatter_edges_kernel<<<(N_EDGES + 255) / 256, 256, 0, stream>>>(ei, cursor, nbr);

    // ---- aggregate: A = bf16(x + gather-sum) ----
    aggregate_kernel<<<(N_NODES + 3) / 4, 256, 0, stream>>>((const float2*)x, offsets, deg,
                                                            nbr, A);

    // ---- MLP (bf16 MFMA) ----
    {
        dim3 grid(M_PAD / 128, HID_DIM / 128);
        gemm_bf16<IN_DIM, true, false><<<grid, 256, 0, stream>>>(A, W1t, b1, H1, nullptr,
                                                                 N_NODES, HID_DIM);
    }
    {
        dim3 grid(M_PAD / 128, HID_DIM / 128);
        gemm_bf16<HID_DIM, true, false><<<grid, 256, 0, stream>>>(H1, W2t, b2, H2, nullptr,
                                                                  N_NODES, HID_DIM);
    }
    {
        dim3 grid(M_PAD / 128, OUT_DIM / 128);
        gemm_bf16<HID_DIM, false, true><<<grid, 256, 0, stream>>>(H2, Wot, bo, out, bi,
                                                                  N_NODES, OUT_DIM);
    }
}

// Round 4
// 567.812 us; speedup vs baseline: 5.8934x; 1.0503x over previous
//
#include <hip/hip_runtime.h>

#define N_NODES  100000
#define M_PAD    100096   // multiple of 128
#define N_EDGES  1600000
#define N_GRAPHS 512
#define IN_DIM   128
#define HID_DIM  256
#define OUT_DIM  128

#define SCAN_B   256
#define NUM_SCAN_BLOCKS ((N_NODES + SCAN_B - 1) / SCAN_B)   // 391

typedef __bf16 bf16x8 __attribute__((ext_vector_type(8)));
typedef __bf16 bf16x2 __attribute__((ext_vector_type(2)));
typedef float  f32x4  __attribute__((ext_vector_type(4)));

// ---------------- degree histogram ----------------
__global__ __launch_bounds__(256) void hist_kernel(const int* __restrict__ ei,
                                                   int* __restrict__ deg) {
    int e = blockIdx.x * blockDim.x + threadIdx.x;
    if (e < N_EDGES) atomicAdd(&deg[ei[N_EDGES + e]], 1);
}

// ---------------- scan step 1: per-block sums ----------------
__global__ __launch_bounds__(SCAN_B) void block_sum_kernel(const int* __restrict__ deg,
                                                           int* __restrict__ blockSums) {
    __shared__ int s[SCAN_B];
    int i = blockIdx.x * SCAN_B + threadIdx.x;
    s[threadIdx.x] = (i < N_NODES) ? deg[i] : 0;
    __syncthreads();
    for (int st = SCAN_B / 2; st > 0; st >>= 1) {
        if (threadIdx.x < st) s[threadIdx.x] += s[threadIdx.x + st];
        __syncthreads();
    }
    if (threadIdx.x == 0) blockSums[blockIdx.x] = s[0];
}

// ---------------- scan step 2: exclusive scan of block sums ----------------
__global__ __launch_bounds__(512) void scan_blocksums_kernel(const int* __restrict__ blockSums,
                                                             int* __restrict__ blockPrefix) {
    __shared__ int s[512];
    int t = threadIdx.x;
    int v = (t < NUM_SCAN_BLOCKS) ? blockSums[t] : 0;
    s[t] = v;
    __syncthreads();
    for (int st = 1; st < 512; st <<= 1) {
        int add = (t >= st) ? s[t - st] : 0;
        __syncthreads();
        s[t] += add;
        __syncthreads();
    }
    if (t < NUM_SCAN_BLOCKS) blockPrefix[t] = s[t] - v;
}

// ---------------- scan step 3: final offsets + cursor init ----------------
__global__ __launch_bounds__(SCAN_B) void scan_final_kernel(const int* __restrict__ deg,
                                                            const int* __restrict__ blockPrefix,
                                                            int* __restrict__ offsets,
                                                            int* __restrict__ cursor) {
    __shared__ int s[SCAN_B];
    int i = blockIdx.x * SCAN_B + threadIdx.x;
    int v = (i < N_NODES) ? deg[i] : 0;
    s[threadIdx.x] = v;
    __syncthreads();
    for (int st = 1; st < SCAN_B; st <<= 1) {
        int add = (threadIdx.x >= st) ? s[threadIdx.x - st] : 0;
        __syncthreads();
        s[threadIdx.x] += add;
        __syncthreads();
    }
    if (i < N_NODES) {
        int excl = blockPrefix[blockIdx.x] + s[threadIdx.x] - v;
        offsets[i] = excl;
        cursor[i] = excl;
    }
}

// ---------------- scatter src ids into CSR buckets ----------------
__global__ __launch_bounds__(256) void scatter_edges_kernel(const int* __restrict__ ei,
                                                            int* __restrict__ cursor,
                                                            int* __restrict__ nbr) {
    int e = blockIdx.x * blockDim.x + threadIdx.x;
    if (e < N_EDGES) {
        int d = ei[N_EDGES + e];
        int s = ei[e];
        int pos = atomicAdd(&cursor[d], 1);
        nbr[pos] = s;
    }
}

// ---------------- gather aggregate: A[v] = bf16(x[v] + sum_{s in nbr(v)} x[s]) ----------------
__global__ __launch_bounds__(256) void aggregate_kernel(const float2* __restrict__ x2,
                                                        const int* __restrict__ offsets,
                                                        const int* __restrict__ deg,
                                                        const int* __restrict__ nbr,
                                                        __bf16* __restrict__ A) {
    int v = blockIdx.x * 4 + (threadIdx.x >> 6);
    v = __builtin_amdgcn_readfirstlane(v);
    int lane = threadIdx.x & 63;
    if (v >= N_NODES) return;
    int off = offsets[v];
    int len = deg[v];
    float2 acc = x2[(size_t)v * (IN_DIM / 2) + lane];
    int i = 0;
    for (; i + 4 <= len; i += 4) {
        int s0 = nbr[off + i + 0];
        int s1 = nbr[off + i + 1];
        int s2 = nbr[off + i + 2];
        int s3 = nbr[off + i + 3];
        float2 a0 = x2[(size_t)s0 * (IN_DIM / 2) + lane];
        float2 a1 = x2[(size_t)s1 * (IN_DIM / 2) + lane];
        float2 a2 = x2[(size_t)s2 * (IN_DIM / 2) + lane];
        float2 a3 = x2[(size_t)s3 * (IN_DIM / 2) + lane];
        acc.x += a0.x + a1.x + a2.x + a3.x;
        acc.y += a0.y + a1.y + a2.y + a3.y;
    }
    for (; i < len; ++i) {
        int s = nbr[off + i];
        float2 a = x2[(size_t)s * (IN_DIM / 2) + lane];
        acc.x += a.x;
        acc.y += a.y;
    }
    bf16x2 h;
    h.x = (__bf16)acc.x;
    h.y = (__bf16)acc.y;
    *(bf16x2*)(A + (size_t)v * IN_DIM + lane * 2) = h;
}

// ---------------- weight convert + transpose: Wt[n][k] = bf16(W[k][n]) ----------------
__global__ __launch_bounds__(256) void convert_transpose_kernel(const float* __restrict__ W,
                                                                __bf16* __restrict__ Wt,
                                                                int K, int N) {
    int i = blockIdx.x * blockDim.x + threadIdx.x;
    if (i < K * N) {
        int k = i / N, n = i % N;
        Wt[(size_t)n * K + k] = (__bf16)W[i];
    }
}

// ---------------- weight-stationary bf16 MFMA GEMM ----------------
// C[M_PAD][N] = act(A[M_PAD][K] @ Bt[N][K]^T + bias), optional pooled atomics.
// Block: 256 thr = 4 waves; whole 128-col weight slab as MFMA B-frags in LDS
// (one barrier total). Each wave owns an independent 32-row strip: A-frags
// global->VGPR (coalesced dwordx4, all K up-front), barrier-free MFMA loop.
template <int K, int N, bool RELU, bool POOL>
__global__ __launch_bounds__(256) void gemm_ws(const __bf16* __restrict__ A,
                                               const __bf16* __restrict__ Bt,
                                               const float* __restrict__ bias,
                                               void* __restrict__ C,
                                               const int* __restrict__ batch) {
    constexpr int KS = K / 32;       // k-steps
    constexpr int P  = 8 * KS;       // B fragments (8 n-tiles x KS)
    __shared__ __bf16 Bs[P * 64 * 8];  // P frags x 64 lanes x 16B

    const int tid  = threadIdx.x;
    const int wave = tid >> 6;
    const int lane = tid & 63;
    const int quad = lane >> 4, l16 = lane & 15;
    const int colbase = blockIdx.y * 128;

    // preload weight slab as fragments (B-frag: n=lane&15, k=quad*8+j)
    for (int p = wave; p < P; p += 4) {
        int t = p / KS, s = p % KS;
        bf16x8 w = *(const bf16x8*)(Bt + (size_t)(colbase + t * 16 + l16) * K + s * 32 + quad * 8);
        *(bf16x8*)(Bs + ((size_t)p * 64 + lane) * 8) = w;
    }
    __syncthreads();

    const int strip = blockIdx.x * 4 + wave;
    const int r0 = strip * 32;

    // A-frags for 2 m-tiles x all k-steps, straight from global (coalesced)
    bf16x8 a[2][KS];
    #pragma unroll
    for (int i = 0; i < 2; ++i)
        #pragma unroll
        for (int s = 0; s < KS; ++s)
            a[i][s] = *(const bf16x8*)(A + (size_t)(r0 + i * 16 + l16) * K + s * 32 + quad * 8);

    f32x4 acc[2][8] = {};
    #pragma unroll
    for (int s = 0; s < KS; ++s)
        #pragma unroll
        for (int t = 0; t < 8; ++t) {
            bf16x8 b = *(const bf16x8*)(Bs + ((size_t)(t * KS + s) * 64 + lane) * 8);
            acc[0][t] = __builtin_amdgcn_mfma_f32_16x16x32_bf16(a[0][s], b, acc[0][t], 0, 0, 0);
            acc[1][t] = __builtin_amdgcn_mfma_f32_16x16x32_bf16(a[1][s], b, acc[1][t], 0, 0, 0);
        }

    // epilogue: C/D layout col=lane&15, row=quad*4+reg
    if (!POOL) {
        #pragma unroll
        for (int i = 0; i < 2; ++i)
            #pragma unroll
            for (int rr = 0; rr < 4; ++rr) {
                size_t m = (size_t)r0 + i * 16 + quad * 4 + rr;
                #pragma unroll
                for (int t = 0; t < 8; ++t) {
                    int c = colbase + t * 16 + l16;
                    float v = acc[i][t][rr] + bias[c];
                    if (RELU) v = fmaxf(v, 0.f);
                    ((__bf16*)C)[m * N + c] = (__bf16)v;
                }
            }
    } else {
        float* out = (float*)C;
        int gfirst = (r0 < N_NODES) ? batch[r0] : -2;
        int glast  = (r0 + 31 < N_NODES) ? batch[r0 + 31] : -1;
        if (gfirst == glast) {
            // whole strip one graph: cross-quad column reduce, 1 atomic/col
            #pragma unroll
            for (int t = 0; t < 8; ++t) {
                float sum = 0.f;
                #pragma unroll
                for (int i = 0; i < 2; ++i)
                    #pragma unroll
                    for (int rr = 0; rr < 4; ++rr) sum += acc[i][t][rr];
                sum += __shfl_xor(sum, 16, 64);
                sum += __shfl_xor(sum, 32, 64);
                if (quad == 0) {
                    int c = colbase + t * 16 + l16;
                    atomicAdd(out + (size_t)gfirst * N + c, sum + 32.f * bias[c]);
                }
            }
        } else {
            #pragma unroll
            for (int i = 0; i < 2; ++i)
                #pragma unroll
                for (int rr = 0; rr < 4; ++rr) {
                    int m = r0 + i * 16 + quad * 4 + rr;
                    if (m < N_NODES) {
                        int g = batch[m];
                        #pragma unroll
                        for (int t = 0; t < 8; ++t) {
                            int c = colbase + t * 16 + l16;
                            atomicAdd(out + (size_t)g * N + c, acc[i][t][rr] + bias[c]);
                        }
                    }
                }
        }
    }
}

extern "C" void kernel_launch(void* const* d_in, const int* in_sizes, int n_in,
                              void* d_out, int out_size, void* d_ws, size_t ws_size,
                              hipStream_t stream) {
    const float* x  = (const float*)d_in[0];
    const int*   ei = (const int*)d_in[1];
    const int*   bi = (const int*)d_in[2];
    const float* W1 = (const float*)d_in[3];
    const float* b1 = (const float*)d_in[4];
    const float* W2 = (const float*)d_in[5];
    const float* b2 = (const float*)d_in[6];
    const float* Wo = (const float*)d_in[7];
    const float* bo = (const float*)d_in[8];
    float* out = (float*)d_out;

    __bf16* A   = (__bf16*)d_ws;                       // [M_PAD][128]
    __bf16* H1  = A   + (size_t)M_PAD * IN_DIM;        // [M_PAD][256]
    __bf16* H2  = H1  + (size_t)M_PAD * HID_DIM;       // [M_PAD][256]
    __bf16* W1t = H2  + (size_t)M_PAD * HID_DIM;       // [256][128]
    __bf16* W2t = W1t + IN_DIM * HID_DIM;              // [256][256]
    __bf16* Wot = W2t + HID_DIM * HID_DIM;             // [128][256]
    int* deg         = (int*)(Wot + HID_DIM * OUT_DIM);
    int* offsets     = deg + N_NODES;
    int* cursor      = offsets + N_NODES;
    int* nbr         = cursor + N_NODES;
    int* blockSums   = nbr + N_EDGES;
    int* blockPrefix = blockSums + NUM_SCAN_BLOCKS;

    hipMemsetAsync(d_out, 0, (size_t)N_GRAPHS * OUT_DIM * sizeof(float), stream);
    hipMemsetAsync(deg, 0, (size_t)N_NODES * sizeof(int), stream);

    // ---- weight conversion (tiny) ----
    convert_transpose_kernel<<<(IN_DIM * HID_DIM + 255) / 256, 256, 0, stream>>>(W1, W1t, IN_DIM, HID_DIM);
    convert_transpose_kernel<<<(HID_DIM * HID_DIM + 255) / 256, 256, 0, stream>>>(W2, W2t, HID_DIM, HID_DIM);
    convert_transpose_kernel<<<(HID_DIM * OUT_DIM + 255) / 256, 256, 0, stream>>>(Wo, Wot, HID_DIM, OUT_DIM);

    // ---- build CSR ----
    hist_kernel<<<(N_EDGES + 255) / 256, 256, 0, stream>>>(ei, deg);
    block_sum_kernel<<<NUM_SCAN_BLOCKS, SCAN_B, 0, stream>>>(deg, blockSums);
    scan_blocksums_kernel<<<1, 512, 0, stream>>>(blockSums, blockPrefix);
    scan_final_kernel<<<NUM_SCAN_BLOCKS, SCAN_B, 0, stream>>>(deg, blockPrefix, offsets, cursor);
    scatter_edges_kernel<<<(N_EDGES + 255) / 256, 256, 0, stream>>>(ei, cursor, nbr);

    // ---- aggregate: A = bf16(x + gather-sum) ----
    aggregate_kernel<<<(N_NODES + 3) / 4, 256, 0, stream>>>((const float2*)x, offsets, deg,
                                                            nbr, A);

    // ---- MLP (weight-stationary bf16 MFMA) ----
    const int NSTRIP_BLK = M_PAD / 32 / 4;  // 782
    {
        dim3 grid(NSTRIP_BLK, HID_DIM / 128);
        gemm_ws<IN_DIM, HID_DIM, true, false><<<grid, 256, 0, stream>>>(A, W1t, b1, H1, nullptr);
    }
    {
        dim3 grid(NSTRIP_BLK, HID_DIM / 128);
        gemm_ws<HID_DIM, HID_DIM, true, false><<<grid, 256, 0, stream>>>(H1, W2t, b2, H2, nullptr);
    }
    {
        dim3 grid(NSTRIP_BLK, OUT_DIM / 128);
        gemm_ws<HID_DIM, OUT_DIM, false, true><<<grid, 256, 0, stream>>>(H2, Wot, bo, out, bi);
    }
}